// Round 3
// baseline (634.920 us; speedup 1.0000x reference)
//
#include <hip/hip_runtime.h>
#include <stdint.h>
#include <string.h>

// B=4,H=16,L=1024,D=64. q,k: fp32 [B,H,L,D]; mask: byte or int32 bool
// (per-block runtime detection); out: fp32 [B,H,L,L].
// out[bh,i,j] = mask ? 0 : sum_d exp(-(qs-ks)^2)/64, rank-paired via stable
// per-(bh,d) argsort of q and k columns.
//
// THIS ROUND: timing probe. Kernels are R1's proven pair, byte-for-byte.
// swd3_phase1 is launched TWICE (idempotent: identical pairs rewritten;
// phase2 consumes afterward). dur_us_new - 555.4 = t(phase1) directly.
// This decides hypothesis (a) "phase1 < 20us, phase2+overhead dominates"
// vs (b) "phase1 ~100us, bound by uncoalesced column loads" — R1 showed
// the sort-structure rewrite was timing-neutral, so the split is unknown.
// NO cooperative launch (R2: container died twice — graph-capture tripwire).
//
// phase1: one WAVE per (bh,d) column-pair, 16 elems/thread. Full bitonic
//         argsort on u64 keys {f2ord(fp32)<<32 | idx}: j=1..8 in-register,
//         j=16..512 via __shfl_xor. Zero barriers, zero LDS sort stages.
//         LDS only as 4KiB wave-private scatter buffer for packed
//         {val fp32 top22, low10 = k-index} output.
// phase2: inline mask-width detect + NT mask prefetch + LDS atomic scatter
//         + masked NT fp32 stores. UNCHANGED from 551-us baseline.

#define LL 1024
#define DD 64
#define NBH 64
#define PAIRS_BYTES ((size_t)NBH * DD * LL * 4)   // 16 MiB

typedef float    vf4   __attribute__((ext_vector_type(4)));
typedef uint32_t vu4   __attribute__((ext_vector_type(4)));
typedef int32_t  vi4   __attribute__((ext_vector_type(4)));

__device__ __forceinline__ uint32_t f2ord(float x) {
    uint32_t u = __float_as_uint(x);
    return (u & 0x80000000u) ? ~u : (u | 0x80000000u);
}
__device__ __forceinline__ float ord2f(uint32_t o) {
    uint32_t u = (o & 0x80000000u) ? (o & 0x7fffffffu) : ~o;
    return __uint_as_float(u);
}
__device__ __forceinline__ void cex(uint64_t& a, uint64_t& b, bool up) {
    const uint64_t lo = a < b ? a : b;
    const uint64_t hi = a < b ? b : a;
    a = up ? lo : hi; b = up ? hi : lo;
}
__device__ __forceinline__ uint64_t shfl64(uint64_t v, int m) {
    const uint32_t lo = __shfl_xor((uint32_t)v, m);
    const uint32_t hi = __shfl_xor((uint32_t)(v >> 32), m);
    return ((uint64_t)hi << 32) | lo;
}

// full bitonic sort of 1024 u64 keys held as x[s], rank r = 16*lane + s
__device__ __forceinline__ void wave_bitonic16(uint64_t x[16], const int lane) {
    // k2 = 2,4,8: in-register, compile-time directions
    #pragma unroll
    for (int lk = 1; lk <= 3; ++lk) {
        const int k2 = 1 << lk;
        #pragma unroll
        for (int j = k2 >> 1; j >= 1; j >>= 1) {
            #pragma unroll
            for (int s = 0; s < 16; ++s)
                if ((s & j) == 0) cex(x[s], x[s | j], ((s & k2) == 0));
        }
    }
    // k2 = 16: direction uniform per thread
    {
        const bool up = ((lane & 1) == 0);
        #pragma unroll
        for (int j = 8; j >= 1; j >>= 1) {
            #pragma unroll
            for (int s = 0; s < 16; ++s)
                if ((s & j) == 0) cex(x[s], x[s | j], up);
        }
    }
    // k2 = 32..1024: cross-lane shfl (j=16..512 -> m=1..32) then in-register
    #pragma unroll
    for (int lk = 5; lk <= 10; ++lk) {
        const bool up = ((lane & (1 << (lk - 4))) == 0);   // lk=10: always up
        #pragma unroll
        for (int m = 1 << (lk - 5); m >= 1; m >>= 1) {
            const bool keepmin = (((lane & m) == 0) == up);
            #pragma unroll
            for (int s = 0; s < 16; ++s) {
                const uint64_t y = shfl64(x[s], m);
                x[s] = keepmin ? (x[s] < y ? x[s] : y)
                               : (x[s] > y ? x[s] : y);
            }
        }
        #pragma unroll
        for (int j = 8; j >= 1; j >>= 1) {
            #pragma unroll
            for (int s = 0; s < 16; ++s)
                if ((s & j) == 0) cex(x[s], x[s | j], up);
        }
    }
}

// ---------- phase 1: 16-elem/thread wave-autonomous bitonic argsort --------
__global__ __launch_bounds__(256, 3) void swd3_phase1(
    const float* __restrict__ q, const float* __restrict__ k,
    uint32_t* __restrict__ pairs)
{
    __shared__ alignas(16) uint32_t pr[4][LL];      // 4 KiB per wave, private

    const int raw  = blockIdx.x;                    // 0..1023
    const int slot = raw >> 3;                      // 0..127
    const int bh   = (raw & 7) * 8 + (slot >> 4);   // XCD swizzle: same bh
    const int dg   = slot & 15;                     //   -> same XCD
    const int t    = threadIdx.x;
    const int w    = t >> 6;                        // wave 0..3
    const int lane = t & 63;
    const int d    = dg * 4 + w;                    // 4 adjacent d per block

    const size_t colbase = (size_t)bh * (LL * DD) + d;

    uint64_t xq[16], xk[16];
    #pragma unroll
    for (int s = 0; s < 16; ++s) {
        const uint32_t e = 16u * (uint32_t)lane + (uint32_t)s;
        xq[s] = ((uint64_t)f2ord(q[colbase + (size_t)e * DD]) << 32) | e;
        xk[s] = ((uint64_t)f2ord(k[colbase + (size_t)e * DD]) << 32) | e;
    }
    wave_bitonic16(xq, lane);
    wave_bitonic16(xk, lane);

    // epilogue: rank r = 16*lane + s pairs q-rank-r with k-rank-r.
    // Scatter packed {val fp32 (top 22 bits), low10 = k-index} by q-index
    // into the wave-private LDS row, then vectorized coalesced store.
    uint32_t* prw = pr[w];
    #pragma unroll
    for (int s = 0; s < 16; ++s) {
        const uint32_t iq = (uint32_t)xq[s] & 1023u;
        const uint32_t ik = (uint32_t)xk[s] & 1023u;
        const float df = ord2f((uint32_t)(xq[s] >> 32))
                       - ord2f((uint32_t)(xk[s] >> 32));
        const float val = __expf(-df * df) * (1.0f / 64.0f);
        prw[iq] = (__float_as_uint(val) & 0xFFFFFC00u) | ik;   // rel err<2^-12
    }
    __asm__ volatile("s_waitcnt lgkmcnt(0)" ::: "memory");  // wave-local drain
    vu4* pp4 = (vu4*)(pairs + ((size_t)bh * DD + d) * LL);
    const vu4* src = (const vu4*)prw;
    #pragma unroll
    for (int r = 0; r < 4; ++r)
        pp4[r * 64 + lane] = src[r * 64 + lane];
}

// ---------- phase 2: inline detect + prefetch + assembly + NT write --------
// UNCHANGED from baseline.
__global__ __launch_bounds__(256) void swd3_phase2(
    const uint32_t* __restrict__ pairs, const void* __restrict__ maskp,
    float* __restrict__ out)
{
    __shared__ alignas(16) float acc[8 * LL];       // 32 KiB
    __shared__ uint32_t sdet[4];

    const int bh = blockIdx.x >> 7;
    const int s  = blockIdx.x & 127;
    const int i0 = s * 8;
    const int t  = threadIdx.x;

    // inline mask-width detect on the globally-shared first 1 KiB of mask
    {
        const uint32_t w = ((const uint32_t*)maskp)[t];
        const uint64_t bal = __ballot(w > 1u);
        if ((t & 63) == 0) sdet[t >> 6] = (bal != 0ull) ? 1u : 0u;
    }

    vf4* acc4 = (vf4*)acc;
    #pragma unroll
    for (int v = 0; v < 8; ++v) {
        vf4 z; z.x = 0.f; z.y = 0.f; z.z = 0.f; z.w = 0.f;
        acc4[v * 256 + t] = z;
    }
    __syncthreads();

    const bool mask_byte =
        ((sdet[0] | sdet[1] | sdet[2] | sdet[3]) != 0u);
    const size_t cellbase = ((size_t)bh << 20) + ((size_t)i0 << 10);

    // prefetch mask into registers (NT); loads fly during the LDS scatter
    uint32_t mb[8];
    vi4      mi[8];
    if (mask_byte) {
        const uint32_t* mp = (const uint32_t*)maskp + (cellbase >> 2);
        #pragma unroll
        for (int v = 0; v < 8; ++v)
            mb[v] = __builtin_nontemporal_load(mp + v * 256 + t);
    } else {
        const vi4* mp = (const vi4*)((const int32_t*)maskp + cellbase);
        #pragma unroll
        for (int v = 0; v < 8; ++v)
            mi[v] = __builtin_nontemporal_load(mp + v * 256 + t);
    }

    // 512 records as 256 uint2: thread t -> dd=t>>2, rows 2*(t&3), 2*(t&3)+1
    {
        const uint32_t* pb = pairs + (size_t)bh * (DD * LL);
        const int dd = t >> 2;
        const uint2 pv = ((const uint2*)(pb + dd * LL + i0))[t & 3];
        const int ii0 = 2 * (t & 3), ii1 = ii0 + 1;
        atomicAdd(&acc[ii0 * LL + (int)(pv.x & 1023u)],
                  __uint_as_float(pv.x & 0xFFFFFC00u));
        atomicAdd(&acc[ii1 * LL + (int)(pv.y & 1023u)],
                  __uint_as_float(pv.y & 0xFFFFFC00u));
    }
    __syncthreads();

    vf4* ob = (vf4*)(out + cellbase);
    #pragma unroll
    for (int v = 0; v < 8; ++v) {
        const int p = v * 256 + t;                  // vf4 group in [0,2048)
        const vf4 a = acc4[p];
        int mx, my, mz, mw2;
        if (mask_byte) {
            const uint32_t m = mb[v];
            mx = (int)(m & 0xFFu); my = (int)((m >> 8) & 0xFFu);
            mz = (int)((m >> 16) & 0xFFu); mw2 = (int)(m >> 24);
        } else {
            mx = mi[v].x; my = mi[v].y; mz = mi[v].z; mw2 = mi[v].w;
        }
        vf4 r;
        r.x = mx  ? 0.f : a.x;
        r.y = my  ? 0.f : a.y;
        r.z = mz  ? 0.f : a.z;
        r.w = mw2 ? 0.f : a.w;
        __builtin_nontemporal_store(r, ob + p);
    }
}

extern "C" void kernel_launch(void* const* d_in, const int* in_sizes, int n_in,
                              void* d_out, int out_size, void* d_ws, size_t ws_size,
                              hipStream_t stream) {
    const float* q = (const float*)d_in[0];
    const float* k = (const float*)d_in[1];
    const void* mask = d_in[2];
    uint32_t* pairs = (uint32_t*)d_ws;

    const bool ws_ok = (ws_size >= PAIRS_BYTES);
    hipError_t e1 = hipSuccess, e2 = hipSuccess;
    (void)hipGetLastError();

    if (ws_ok) {
        // PROBE: phase1 launched twice (idempotent). dur_us - 555.4 = t(p1).
        swd3_phase1<<<NBH * DD / 4, 256, 0, stream>>>(q, k, pairs);
        swd3_phase1<<<NBH * DD / 4, 256, 0, stream>>>(q, k, pairs);
        e1 = hipGetLastError();
        swd3_phase2<<<NBH * 128, 256, 0, stream>>>(pairs, mask, (float*)d_out);
        e2 = hipGetLastError();
    }

    if (!ws_ok || e1 != hipSuccess || e2 != hipSuccess) {
        // Diagnostic stamp (fp32 codes): absmax reveals which enqueue failed.
        static float h_stamp[8];
        h_stamp[0] = !ws_ok ? (9000.0f + (float)(ws_size >> 20))
                            : (1000.0f + (float)(int)e1);
        h_stamp[1] = 2000.0f + (float)(int)e2;
        h_stamp[2] = h_stamp[0];
        h_stamp[3] = h_stamp[1];
        hipMemcpyAsync(d_out, h_stamp, sizeof(h_stamp),
                       hipMemcpyHostToDevice, stream);
    }
}

// Round 4
// 551.795 us; speedup vs baseline: 1.1506x; 1.1506x over previous
//
#include <hip/hip_runtime.h>
#include <stdint.h>
#include <string.h>

// B=4,H=16,L=1024,D=64. q,k: fp32 [B,H,L,D]; mask: byte or int32 bool
// (per-block runtime detection); out: fp32 [B,H,L,L].
// out[bh,i,j] = mask ? 0 : sum_d exp(-(qs-ks)^2)/64, rank-paired via stable
// per-(bh,d) argsort of q and k columns.
//
// R3 probe: t(phase1) = 634.9-555.4 = 79.5us; fixed+p2 = 475.9us.
// Theory: phase1 is bound by 256B-stride column loads (64 line-transactions
// per load instr, 4B/64B used). THIS ROUND:
//   kernel0 swd3_transpose: LDS 64x64 tile transpose q,k -> qt,kt[bh][d][e]
//           with f2ord fused (u32 ord keys). ~64MiB traffic ~ 10us.
//   phase1: loads become 4x vu4/lane, fully coalesced (slot ownership at
//           load time is arbitrary for a bitonic network; true e packed in
//           key low bits). Sort/epilogue unchanged from R1.
//   phase2: bh mapping changed to XCD = bh>>3 (matches phase1 writer XCD;
//           pairs reads become L2-local instead of cross-XCD dirty lines).
// All single launches. p1_new + transpose = dur - 475.9 (no probe needed).
// NO cooperative launch (R2 lesson: container died twice).

#define LL 1024
#define DD 64
#define NBH 64
#define MAT_WORDS ((size_t)NBH * DD * LL)          // 4 Mi words = 16 MiB
#define WS_BYTES (3 * MAT_WORDS * 4)               // pairs + qt + kt = 48 MiB

typedef float    vf4   __attribute__((ext_vector_type(4)));
typedef uint32_t vu4   __attribute__((ext_vector_type(4)));
typedef int32_t  vi4   __attribute__((ext_vector_type(4)));

__device__ __forceinline__ uint32_t f2ord(float x) {
    uint32_t u = __float_as_uint(x);
    return (u & 0x80000000u) ? ~u : (u | 0x80000000u);
}
__device__ __forceinline__ float ord2f(uint32_t o) {
    uint32_t u = (o & 0x80000000u) ? (o & 0x7fffffffu) : ~o;
    return __uint_as_float(u);
}
__device__ __forceinline__ void cex(uint64_t& a, uint64_t& b, bool up) {
    const uint64_t lo = a < b ? a : b;
    const uint64_t hi = a < b ? b : a;
    a = up ? lo : hi; b = up ? hi : lo;
}
__device__ __forceinline__ uint64_t shfl64(uint64_t v, int m) {
    const uint32_t lo = __shfl_xor((uint32_t)v, m);
    const uint32_t hi = __shfl_xor((uint32_t)(v >> 32), m);
    return ((uint64_t)hi << 32) | lo;
}

// full bitonic sort of 1024 u64 keys held as x[s], final rank r = 16*lane+s
__device__ __forceinline__ void wave_bitonic16(uint64_t x[16], const int lane) {
    #pragma unroll
    for (int lk = 1; lk <= 3; ++lk) {               // k2 = 2,4,8: in-register
        const int k2 = 1 << lk;
        #pragma unroll
        for (int j = k2 >> 1; j >= 1; j >>= 1) {
            #pragma unroll
            for (int s = 0; s < 16; ++s)
                if ((s & j) == 0) cex(x[s], x[s | j], ((s & k2) == 0));
        }
    }
    {                                               // k2 = 16: uniform dir
        const bool up = ((lane & 1) == 0);
        #pragma unroll
        for (int j = 8; j >= 1; j >>= 1) {
            #pragma unroll
            for (int s = 0; s < 16; ++s)
                if ((s & j) == 0) cex(x[s], x[s | j], up);
        }
    }
    #pragma unroll
    for (int lk = 5; lk <= 10; ++lk) {              // k2 = 32..1024
        const bool up = ((lane & (1 << (lk - 4))) == 0);   // lk=10: always up
        #pragma unroll
        for (int m = 1 << (lk - 5); m >= 1; m >>= 1) {
            const bool keepmin = (((lane & m) == 0) == up);
            #pragma unroll
            for (int s = 0; s < 16; ++s) {
                const uint64_t y = shfl64(x[s], m);
                x[s] = keepmin ? (x[s] < y ? x[s] : y)
                               : (x[s] > y ? x[s] : y);
            }
        }
        #pragma unroll
        for (int j = 8; j >= 1; j >>= 1) {
            #pragma unroll
            for (int s = 0; s < 16; ++s)
                if ((s & j) == 0) cex(x[s], x[s | j], up);
        }
    }
}

// ---------- kernel 0: tile-transpose q,k -> qt,kt[bh][d][e] as f2ord u32 ---
__global__ __launch_bounds__(256) void swd3_transpose(
    const float* __restrict__ q, const float* __restrict__ k,
    uint32_t* __restrict__ qt, uint32_t* __restrict__ kt)
{
    __shared__ uint32_t tq[64][65];                 // +1 pad: col reads
    __shared__ uint32_t tk[64][65];                 //   conflict-free

    const int b  = blockIdx.x;                      // 0..1023
    const int bh = (b & 7) * 8 + ((b >> 3) & 7);    // XCD b%8 <-> bh>>3
    const int e0 = (b >> 6) * 64;                   // e-tile 0..15
    const int t  = threadIdx.x;

    const size_t base = (size_t)bh * (LL * DD);
    #pragma unroll
    for (int i = 0; i < 4; ++i) {
        const int idx = i * 256 + t;                // 0..1023
        const int r   = idx >> 4;                   // row in tile 0..63
        const int c   = (idx & 15) * 4;             // col 0,4,..,60
        const vf4 vq = *(const vf4*)(q + base + (size_t)(e0 + r) * DD + c);
        const vf4 vk = *(const vf4*)(k + base + (size_t)(e0 + r) * DD + c);
        tq[r][c + 0] = f2ord(vq.x); tq[r][c + 1] = f2ord(vq.y);
        tq[r][c + 2] = f2ord(vq.z); tq[r][c + 3] = f2ord(vq.w);
        tk[r][c + 0] = f2ord(vk.x); tk[r][c + 1] = f2ord(vk.y);
        tk[r][c + 2] = f2ord(vk.z); tk[r][c + 3] = f2ord(vk.w);
    }
    __syncthreads();
    #pragma unroll
    for (int i = 0; i < 4; ++i) {
        const int idx = i * 256 + t;
        const int d   = idx >> 4;                   // out row (dim) 0..63
        const int c   = (idx & 15) * 4;             // e-offset in tile
        vu4 v;
        v.x = tq[c + 0][d]; v.y = tq[c + 1][d];
        v.z = tq[c + 2][d]; v.w = tq[c + 3][d];
        *(vu4*)(qt + base + (size_t)d * LL + e0 + c) = v;
        v.x = tk[c + 0][d]; v.y = tk[c + 1][d];
        v.z = tk[c + 2][d]; v.w = tk[c + 3][d];
        *(vu4*)(kt + base + (size_t)d * LL + e0 + c) = v;
    }
}

// ---------- phase 1: coalesced loads + wave-autonomous bitonic argsort -----
__global__ __launch_bounds__(256, 3) void swd3_phase1(
    const uint32_t* __restrict__ qt, const uint32_t* __restrict__ kt,
    uint32_t* __restrict__ pairs)
{
    __shared__ alignas(16) uint32_t pr[4][LL];      // 4 KiB per wave, private

    const int raw  = blockIdx.x;                    // 0..1023
    const int slot = raw >> 3;                      // 0..127
    const int bh   = (raw & 7) * 8 + (slot >> 4);   // XCD raw%8 <-> bh>>3
    const int dg   = slot & 15;
    const int t    = threadIdx.x;
    const int w    = t >> 6;                        // wave 0..3
    const int lane = t & 63;
    const int d    = dg * 4 + w;

    const uint32_t* colq = qt + (size_t)bh * (DD * LL) + (size_t)d * LL;
    const uint32_t* colk = kt + (size_t)bh * (DD * LL) + (size_t)d * LL;

    // coalesced: instr r covers 1024B contiguous; slot ownership arbitrary
    // for the network — true element index e packed into key low bits.
    uint64_t xq[16], xk[16];
    #pragma unroll
    for (int r = 0; r < 4; ++r) {
        const vu4 vq = *(const vu4*)(colq + 256 * r + 4 * lane);
        const vu4 vk = *(const vu4*)(colk + 256 * r + 4 * lane);
        const uint32_t eb = 256u * r + 4u * lane;
        xq[4 * r + 0] = ((uint64_t)vq.x << 32) | (eb + 0);
        xq[4 * r + 1] = ((uint64_t)vq.y << 32) | (eb + 1);
        xq[4 * r + 2] = ((uint64_t)vq.z << 32) | (eb + 2);
        xq[4 * r + 3] = ((uint64_t)vq.w << 32) | (eb + 3);
        xk[4 * r + 0] = ((uint64_t)vk.x << 32) | (eb + 0);
        xk[4 * r + 1] = ((uint64_t)vk.y << 32) | (eb + 1);
        xk[4 * r + 2] = ((uint64_t)vk.z << 32) | (eb + 2);
        xk[4 * r + 3] = ((uint64_t)vk.w << 32) | (eb + 3);
    }
    wave_bitonic16(xq, lane);
    wave_bitonic16(xk, lane);

    // rank r pairs q-rank-r with k-rank-r; scatter packed
    // {val fp32 top22, low10 = k-index} by q-index into wave-private LDS.
    uint32_t* prw = pr[w];
    #pragma unroll
    for (int s = 0; s < 16; ++s) {
        const uint32_t iq = (uint32_t)xq[s] & 1023u;
        const uint32_t ik = (uint32_t)xk[s] & 1023u;
        const float df = ord2f((uint32_t)(xq[s] >> 32))
                       - ord2f((uint32_t)(xk[s] >> 32));
        const float val = __expf(-df * df) * (1.0f / 64.0f);
        prw[iq] = (__float_as_uint(val) & 0xFFFFFC00u) | ik;   // rel err<2^-12
    }
    __asm__ volatile("s_waitcnt lgkmcnt(0)" ::: "memory");  // wave-local drain
    vu4* pp4 = (vu4*)(pairs + ((size_t)bh * DD + d) * LL);
    const vu4* src = (const vu4*)prw;
    #pragma unroll
    for (int r = 0; r < 4; ++r)
        pp4[r * 64 + lane] = src[r * 64 + lane];
}

// ---------- phase 2: inline detect + prefetch + assembly + NT write --------
// Body unchanged from baseline; bh mapping now XCD-matched to phase1 writer.
__global__ __launch_bounds__(256) void swd3_phase2(
    const uint32_t* __restrict__ pairs, const void* __restrict__ maskp,
    float* __restrict__ out)
{
    __shared__ alignas(16) float acc[8 * LL];       // 32 KiB
    __shared__ uint32_t sdet[4];

    const int b  = blockIdx.x;                      // 0..8191
    const int bh = (b & 7) * 8 + ((b >> 3) & 7);    // XCD b%8 <-> bh>>3
    const int st = b >> 6;                          // stripe 0..127
    const int i0 = st * 8;
    const int t  = threadIdx.x;

    // inline mask-width detect on the globally-shared first 1 KiB of mask
    {
        const uint32_t w = ((const uint32_t*)maskp)[t];
        const uint64_t bal = __ballot(w > 1u);
        if ((t & 63) == 0) sdet[t >> 6] = (bal != 0ull) ? 1u : 0u;
    }

    vf4* acc4 = (vf4*)acc;
    #pragma unroll
    for (int v = 0; v < 8; ++v) {
        vf4 z; z.x = 0.f; z.y = 0.f; z.z = 0.f; z.w = 0.f;
        acc4[v * 256 + t] = z;
    }
    __syncthreads();

    const bool mask_byte =
        ((sdet[0] | sdet[1] | sdet[2] | sdet[3]) != 0u);
    const size_t cellbase = ((size_t)bh << 20) + ((size_t)i0 << 10);

    // prefetch mask into registers (NT); loads fly during the LDS scatter
    uint32_t mb[8];
    vi4      mi[8];
    if (mask_byte) {
        const uint32_t* mp = (const uint32_t*)maskp + (cellbase >> 2);
        #pragma unroll
        for (int v = 0; v < 8; ++v)
            mb[v] = __builtin_nontemporal_load(mp + v * 256 + t);
    } else {
        const vi4* mp = (const vi4*)((const int32_t*)maskp + cellbase);
        #pragma unroll
        for (int v = 0; v < 8; ++v)
            mi[v] = __builtin_nontemporal_load(mp + v * 256 + t);
    }

    // 512 records as 256 uint2: thread t -> dd=t>>2, rows 2*(t&3), 2*(t&3)+1
    {
        const uint32_t* pb = pairs + (size_t)bh * (DD * LL);
        const int dd = t >> 2;
        const uint2 pv = ((const uint2*)(pb + dd * LL + i0))[t & 3];
        const int ii0 = 2 * (t & 3), ii1 = ii0 + 1;
        atomicAdd(&acc[ii0 * LL + (int)(pv.x & 1023u)],
                  __uint_as_float(pv.x & 0xFFFFFC00u));
        atomicAdd(&acc[ii1 * LL + (int)(pv.y & 1023u)],
                  __uint_as_float(pv.y & 0xFFFFFC00u));
    }
    __syncthreads();

    vf4* ob = (vf4*)(out + cellbase);
    #pragma unroll
    for (int v = 0; v < 8; ++v) {
        const int p = v * 256 + t;                  // vf4 group in [0,2048)
        const vf4 a = acc4[p];
        int mx, my, mz, mw2;
        if (mask_byte) {
            const uint32_t m = mb[v];
            mx = (int)(m & 0xFFu); my = (int)((m >> 8) & 0xFFu);
            mz = (int)((m >> 16) & 0xFFu); mw2 = (int)(m >> 24);
        } else {
            mx = mi[v].x; my = mi[v].y; mz = mi[v].z; mw2 = mi[v].w;
        }
        vf4 r;
        r.x = mx  ? 0.f : a.x;
        r.y = my  ? 0.f : a.y;
        r.z = mz  ? 0.f : a.z;
        r.w = mw2 ? 0.f : a.w;
        __builtin_nontemporal_store(r, ob + p);
    }
}

extern "C" void kernel_launch(void* const* d_in, const int* in_sizes, int n_in,
                              void* d_out, int out_size, void* d_ws, size_t ws_size,
                              hipStream_t stream) {
    const float* q = (const float*)d_in[0];
    const float* k = (const float*)d_in[1];
    const void* mask = d_in[2];
    uint32_t* pairs = (uint32_t*)d_ws;
    uint32_t* qt = pairs + MAT_WORDS;
    uint32_t* kt = qt + MAT_WORDS;

    const bool ws_ok = (ws_size >= WS_BYTES);
    hipError_t e0 = hipSuccess, e1 = hipSuccess, e2 = hipSuccess;
    (void)hipGetLastError();

    if (ws_ok) {
        swd3_transpose<<<NBH * 16, 256, 0, stream>>>(q, k, qt, kt);
        e0 = hipGetLastError();
        swd3_phase1<<<NBH * DD / 4, 256, 0, stream>>>(qt, kt, pairs);
        e1 = hipGetLastError();
        swd3_phase2<<<NBH * 128, 256, 0, stream>>>(pairs, mask, (float*)d_out);
        e2 = hipGetLastError();
    }

    if (!ws_ok || e0 != hipSuccess || e1 != hipSuccess || e2 != hipSuccess) {
        // Diagnostic stamp (fp32 codes): absmax reveals which enqueue failed.
        static float h_stamp[8];
        h_stamp[0] = !ws_ok ? (9000.0f + (float)(ws_size >> 20))
                            : (1000.0f + (float)(int)e0);
        h_stamp[1] = 2000.0f + (float)(int)e1;
        h_stamp[2] = 3000.0f + (float)(int)e2;
        h_stamp[3] = h_stamp[0];
        hipMemcpyAsync(d_out, h_stamp, sizeof(h_stamp),
                       hipMemcpyHostToDevice, stream);
    }
}

// Round 5
// 507.009 us; speedup vs baseline: 1.2523x; 1.0883x over previous
//
#include <hip/hip_runtime.h>
#include <stdint.h>
#include <string.h>

// B=4,H=16,L=1024,D=64. q,k: fp32 [B,H,L,D]; mask: byte or int32 bool
// (per-block runtime detection); out: fp32 [B,H,L,L].
// out[bh,i,j] = mask ? 0 : sum_d exp(-(qs-ks)^2)/64, rank-paired via stable
// per-(bh,d) argsort of q and k columns.
//
// Ledger: p1(R1 shfl sort)=79.5us; R4: transpose+coalesced p1 = 75.9 combined
// -> sort exchange cost dominates. 21 cross-lane steps/sort were all DS-pipe
// (ds_swizzle/bpermute: 672 DS instrs/sort, ~36us chip-wide on 1 LDS pipe/CU).
// THIS ROUND: mirror-first all-ascending bitonic + DPP exchanges.
//   - merges start with mirror CE (i <-> S-1-i): lane-mirrors <=16 lanes are
//     single DPP ops (quad_perm 0x1B, row_half_mirror 0x141, row_mirror 0x140)
//   - xor^1/^2 = quad_perm DPP; ^4 = ^7dpp∘^3dpp; ^8 = ^15dpp∘^7dpp
//   - only ^16 (swz 0x401F), ^31 (swz 0x7C1F), ^63 (ds_bpermute) stay DS
//   DS steps/sort: 21 -> 3. Direction logic eliminated (all ascending).
// transpose kernel + coalesced loads + epilogue + phase2: UNCHANGED from R4.
// NO cooperative launch (R2 lesson).

#define LL 1024
#define DD 64
#define NBH 64
#define MAT_WORDS ((size_t)NBH * DD * LL)          // 4 Mi words = 16 MiB
#define WS_BYTES (3 * MAT_WORDS * 4)               // pairs + qt + kt = 48 MiB

typedef float    vf4   __attribute__((ext_vector_type(4)));
typedef uint32_t vu4   __attribute__((ext_vector_type(4)));
typedef int32_t  vi4   __attribute__((ext_vector_type(4)));

__device__ __forceinline__ uint32_t f2ord(float x) {
    uint32_t u = __float_as_uint(x);
    return (u & 0x80000000u) ? ~u : (u | 0x80000000u);
}
__device__ __forceinline__ float ord2f(uint32_t o) {
    uint32_t u = (o & 0x80000000u) ? (o & 0x7fffffffu) : ~o;
    return __uint_as_float(u);
}

// ---- cross-lane fetch primitives (u64 as 2 dwords) ----
template <int CTRL>
__device__ __forceinline__ uint64_t dpp64(uint64_t v) {
    const uint32_t lo = (uint32_t)__builtin_amdgcn_update_dpp(
        0, (int)(uint32_t)v, CTRL, 0xF, 0xF, true);
    const uint32_t hi = (uint32_t)__builtin_amdgcn_update_dpp(
        0, (int)(uint32_t)(v >> 32), CTRL, 0xF, 0xF, true);
    return ((uint64_t)hi << 32) | lo;
}
template <int PATT>
__device__ __forceinline__ uint64_t swz64(uint64_t v) {
    const uint32_t lo = (uint32_t)__builtin_amdgcn_ds_swizzle(
        (int)(uint32_t)v, PATT);
    const uint32_t hi = (uint32_t)__builtin_amdgcn_ds_swizzle(
        (int)(uint32_t)(v >> 32), PATT);
    return ((uint64_t)hi << 32) | lo;
}
__device__ __forceinline__ uint64_t bper64(uint64_t v, int addr) {
    const uint32_t lo = (uint32_t)__builtin_amdgcn_ds_bpermute(
        addr, (int)(uint32_t)v);
    const uint32_t hi = (uint32_t)__builtin_amdgcn_ds_bpermute(
        addr, (int)(uint32_t)(v >> 32));
    return ((uint64_t)hi << 32) | lo;
}
// lane-xor fetchers: x1,x2 direct quad_perm; x4=^7∘^3, x8=^15∘^7 composed;
// x3,x7,x15 are lane-mirrors; x16,x31 ds_swizzle BitMode.
__device__ __forceinline__ uint64_t fx1 (uint64_t v){ return dpp64<0xB1>(v); }
__device__ __forceinline__ uint64_t fx2 (uint64_t v){ return dpp64<0x4E>(v); }
__device__ __forceinline__ uint64_t fx3 (uint64_t v){ return dpp64<0x1B>(v); }
__device__ __forceinline__ uint64_t fx4 (uint64_t v){ return dpp64<0x1B>(dpp64<0x141>(v)); }
__device__ __forceinline__ uint64_t fx7 (uint64_t v){ return dpp64<0x141>(v); }
__device__ __forceinline__ uint64_t fx8 (uint64_t v){ return dpp64<0x141>(dpp64<0x140>(v)); }
__device__ __forceinline__ uint64_t fx15(uint64_t v){ return dpp64<0x140>(v); }
__device__ __forceinline__ uint64_t fx16(uint64_t v){ return swz64<0x401F>(v); }
__device__ __forceinline__ uint64_t fx31(uint64_t v){ return swz64<0x7C1F>(v); }

// full ascending sort of 1024 u64 keys, element p = 16*lane + s.
// Mirror-first bitonic: every merge S starts with mirror CE (p <-> S-1-p),
// then xor steps S/4..1, ALL directions ascending (no up/down logic).
__device__ __forceinline__ void wave_sort1024(uint64_t x[16], const int lane,
                                              const int addr63)
{
    auto cexA = [](uint64_t& a, uint64_t& b) {
        const uint64_t lo = a < b ? a : b;
        const uint64_t hi = a < b ? b : a;
        a = lo; b = hi;
    };
    auto sel = [](uint64_t xv, uint64_t y, bool km) {
        return ((xv < y) == km) ? xv : y;      // km: keep min, else keep max
    };

#define TAIL4() do { _Pragma("unroll") \
    for (int j = 8; j >= 1; j >>= 1) { _Pragma("unroll") \
        for (int s = 0; s < 16; ++s) \
            if (!(s & j)) cexA(x[s], x[s | j]); } } while (0)

// mirror CE across lanes: pair (lane,s) <-> (partner, 15-s); fetch both
// directions before updating (DPP reads are lockstep per instruction).
#define MIRROR(F, KM) do { _Pragma("unroll") \
    for (int i = 0; i < 8; ++i) { \
        const uint64_t ya = F(x[15 - i]); \
        const uint64_t yb = F(x[i]); \
        x[i]      = sel(x[i],      ya, (KM)); \
        x[15 - i] = sel(x[15 - i], yb, (KM)); } } while (0)

#define XORST(F, KM) do { _Pragma("unroll") \
    for (int s = 0; s < 16; ++s) { \
        const uint64_t y = F(x[s]); \
        x[s] = sel(x[s], y, (KM)); } } while (0)

    // ---- in-register prelude: S = 2,4,8,16 (per-lane 16-elem sort) ----
    #pragma unroll
    for (int s = 0; s < 16; s += 2) cexA(x[s], x[s + 1]);          // S=2
    #pragma unroll
    for (int b = 0; b < 16; b += 4) {                              // S=4 M
        cexA(x[b], x[b + 3]); cexA(x[b + 1], x[b + 2]);
    }
    #pragma unroll
    for (int s = 0; s < 16; s += 2) cexA(x[s], x[s + 1]);          // S=4 j1
    #pragma unroll
    for (int b = 0; b < 16; b += 8) {                              // S=8 M
        cexA(x[b], x[b + 7]); cexA(x[b + 1], x[b + 6]);
        cexA(x[b + 2], x[b + 5]); cexA(x[b + 3], x[b + 4]);
    }
    #pragma unroll
    for (int j = 2; j >= 1; j >>= 1) {                             // S=8 tail
        #pragma unroll
        for (int s = 0; s < 16; ++s)
            if (!(s & j)) cexA(x[s], x[s | j]);
    }
    #pragma unroll
    for (int i = 0; i < 8; ++i) cexA(x[i], x[15 - i]);             // S=16 M
    #pragma unroll
    for (int j = 4; j >= 1; j >>= 1) {                             // S=16 tail
        #pragma unroll
        for (int s = 0; s < 16; ++s)
            if (!(s & j)) cexA(x[s], x[s | j]);
    }

    // ---- cross-lane merges ----
    { const bool km = (lane & 1) == 0;                 // S=32
      MIRROR(fx1, km); TAIL4(); }
    { const bool kmM = (lane & 2) == 0;                // S=64
      MIRROR(fx3, kmM);
      const bool k1 = (lane & 1) == 0; XORST(fx1, k1); TAIL4(); }
    { const bool kmM = (lane & 4) == 0;                // S=128
      MIRROR(fx7, kmM);
      const bool k2 = (lane & 2) == 0; XORST(fx2, k2);
      const bool k1 = (lane & 1) == 0; XORST(fx1, k1); TAIL4(); }
    { const bool kmM = (lane & 8) == 0;                // S=256
      MIRROR(fx15, kmM);
      const bool k4 = (lane & 4) == 0; XORST(fx4, k4);
      const bool k2 = (lane & 2) == 0; XORST(fx2, k2);
      const bool k1 = (lane & 1) == 0; XORST(fx1, k1); TAIL4(); }
    { const bool kmM = (lane & 16) == 0;               // S=512
      MIRROR(fx31, kmM);
      const bool k8 = (lane & 8) == 0; XORST(fx8, k8);
      const bool k4 = (lane & 4) == 0; XORST(fx4, k4);
      const bool k2 = (lane & 2) == 0; XORST(fx2, k2);
      const bool k1 = (lane & 1) == 0; XORST(fx1, k1); TAIL4(); }
    { const bool kmM = (lane & 32) == 0;               // S=1024
      #pragma unroll
      for (int i = 0; i < 8; ++i) {                    // mirror ^63: bpermute
          const uint64_t ya = bper64(x[15 - i], addr63);
          const uint64_t yb = bper64(x[i], addr63);
          x[i]      = sel(x[i],      ya, kmM);
          x[15 - i] = sel(x[15 - i], yb, kmM);
      }
      const bool k16 = (lane & 16) == 0; XORST(fx16, k16);
      const bool k8  = (lane & 8)  == 0; XORST(fx8,  k8);
      const bool k4  = (lane & 4)  == 0; XORST(fx4,  k4);
      const bool k2  = (lane & 2)  == 0; XORST(fx2,  k2);
      const bool k1  = (lane & 1)  == 0; XORST(fx1,  k1); TAIL4(); }

#undef TAIL4
#undef MIRROR
#undef XORST
}

// ---------- kernel 0: tile-transpose q,k -> qt,kt[bh][d][e] as f2ord u32 ---
__global__ __launch_bounds__(256) void swd3_transpose(
    const float* __restrict__ q, const float* __restrict__ k,
    uint32_t* __restrict__ qt, uint32_t* __restrict__ kt)
{
    __shared__ uint32_t tq[64][65];                 // +1 pad: col reads
    __shared__ uint32_t tk[64][65];                 //   conflict-free

    const int b  = blockIdx.x;                      // 0..1023
    const int bh = (b & 7) * 8 + ((b >> 3) & 7);    // XCD b%8 <-> bh>>3
    const int e0 = (b >> 6) * 64;                   // e-tile 0..15
    const int t  = threadIdx.x;

    const size_t base = (size_t)bh * (LL * DD);
    #pragma unroll
    for (int i = 0; i < 4; ++i) {
        const int idx = i * 256 + t;                // 0..1023
        const int r   = idx >> 4;                   // row in tile 0..63
        const int c   = (idx & 15) * 4;             // col 0,4,..,60
        const vf4 vq = *(const vf4*)(q + base + (size_t)(e0 + r) * DD + c);
        const vf4 vk = *(const vf4*)(k + base + (size_t)(e0 + r) * DD + c);
        tq[r][c + 0] = f2ord(vq.x); tq[r][c + 1] = f2ord(vq.y);
        tq[r][c + 2] = f2ord(vq.z); tq[r][c + 3] = f2ord(vq.w);
        tk[r][c + 0] = f2ord(vk.x); tk[r][c + 1] = f2ord(vk.y);
        tk[r][c + 2] = f2ord(vk.z); tk[r][c + 3] = f2ord(vk.w);
    }
    __syncthreads();
    #pragma unroll
    for (int i = 0; i < 4; ++i) {
        const int idx = i * 256 + t;
        const int d   = idx >> 4;                   // out row (dim) 0..63
        const int c   = (idx & 15) * 4;             // e-offset in tile
        vu4 v;
        v.x = tq[c + 0][d]; v.y = tq[c + 1][d];
        v.z = tq[c + 2][d]; v.w = tq[c + 3][d];
        *(vu4*)(qt + base + (size_t)d * LL + e0 + c) = v;
        v.x = tk[c + 0][d]; v.y = tk[c + 1][d];
        v.z = tk[c + 2][d]; v.w = tk[c + 3][d];
        *(vu4*)(kt + base + (size_t)d * LL + e0 + c) = v;
    }
}

// ---------- phase 1: coalesced loads + mirror/DPP bitonic argsort ----------
__global__ __launch_bounds__(256, 3) void swd3_phase1(
    const uint32_t* __restrict__ qt, const uint32_t* __restrict__ kt,
    uint32_t* __restrict__ pairs)
{
    __shared__ alignas(16) uint32_t pr[4][LL];      // 4 KiB per wave, private

    const int raw  = blockIdx.x;                    // 0..1023
    const int slot = raw >> 3;                      // 0..127
    const int bh   = (raw & 7) * 8 + (slot >> 4);   // XCD raw%8 <-> bh>>3
    const int dg   = slot & 15;
    const int t    = threadIdx.x;
    const int w    = t >> 6;                        // wave 0..3
    const int lane = t & 63;
    const int d    = dg * 4 + w;
    const int addr63 = (lane ^ 63) << 2;            // bpermute byte addr

    const uint32_t* colq = qt + (size_t)bh * (DD * LL) + (size_t)d * LL;
    const uint32_t* colk = kt + (size_t)bh * (DD * LL) + (size_t)d * LL;

    // coalesced: instr r covers 1024B contiguous; slot ownership arbitrary
    // for the network — true element index e packed into key low bits.
    uint64_t xq[16], xk[16];
    #pragma unroll
    for (int r = 0; r < 4; ++r) {
        const vu4 vq = *(const vu4*)(colq + 256 * r + 4 * lane);
        const vu4 vk = *(const vu4*)(colk + 256 * r + 4 * lane);
        const uint32_t eb = 256u * r + 4u * lane;
        xq[4 * r + 0] = ((uint64_t)vq.x << 32) | (eb + 0);
        xq[4 * r + 1] = ((uint64_t)vq.y << 32) | (eb + 1);
        xq[4 * r + 2] = ((uint64_t)vq.z << 32) | (eb + 2);
        xq[4 * r + 3] = ((uint64_t)vq.w << 32) | (eb + 3);
        xk[4 * r + 0] = ((uint64_t)vk.x << 32) | (eb + 0);
        xk[4 * r + 1] = ((uint64_t)vk.y << 32) | (eb + 1);
        xk[4 * r + 2] = ((uint64_t)vk.z << 32) | (eb + 2);
        xk[4 * r + 3] = ((uint64_t)vk.w << 32) | (eb + 3);
    }
    wave_sort1024(xq, lane, addr63);
    wave_sort1024(xk, lane, addr63);

    // rank r pairs q-rank-r with k-rank-r; scatter packed
    // {val fp32 top22, low10 = k-index} by q-index into wave-private LDS.
    uint32_t* prw = pr[w];
    #pragma unroll
    for (int s = 0; s < 16; ++s) {
        const uint32_t iq = (uint32_t)xq[s] & 1023u;
        const uint32_t ik = (uint32_t)xk[s] & 1023u;
        const float df = ord2f((uint32_t)(xq[s] >> 32))
                       - ord2f((uint32_t)(xk[s] >> 32));
        const float val = __expf(-df * df) * (1.0f / 64.0f);
        prw[iq] = (__float_as_uint(val) & 0xFFFFFC00u) | ik;   // rel err<2^-12
    }
    __asm__ volatile("s_waitcnt lgkmcnt(0)" ::: "memory");  // wave-local drain
    vu4* pp4 = (vu4*)(pairs + ((size_t)bh * DD + d) * LL);
    const vu4* src = (const vu4*)prw;
    #pragma unroll
    for (int r = 0; r < 4; ++r)
        pp4[r * 64 + lane] = src[r * 64 + lane];
}

// ---------- phase 2: inline detect + prefetch + assembly + NT write --------
// UNCHANGED from R4 (XCD mapping matched to phase1 writer).
__global__ __launch_bounds__(256) void swd3_phase2(
    const uint32_t* __restrict__ pairs, const void* __restrict__ maskp,
    float* __restrict__ out)
{
    __shared__ alignas(16) float acc[8 * LL];       // 32 KiB
    __shared__ uint32_t sdet[4];

    const int b  = blockIdx.x;                      // 0..8191
    const int bh = (b & 7) * 8 + ((b >> 3) & 7);    // XCD b%8 <-> bh>>3
    const int st = b >> 6;                          // stripe 0..127
    const int i0 = st * 8;
    const int t  = threadIdx.x;

    // inline mask-width detect on the globally-shared first 1 KiB of mask
    {
        const uint32_t w = ((const uint32_t*)maskp)[t];
        const uint64_t bal = __ballot(w > 1u);
        if ((t & 63) == 0) sdet[t >> 6] = (bal != 0ull) ? 1u : 0u;
    }

    vf4* acc4 = (vf4*)acc;
    #pragma unroll
    for (int v = 0; v < 8; ++v) {
        vf4 z; z.x = 0.f; z.y = 0.f; z.z = 0.f; z.w = 0.f;
        acc4[v * 256 + t] = z;
    }
    __syncthreads();

    const bool mask_byte =
        ((sdet[0] | sdet[1] | sdet[2] | sdet[3]) != 0u);
    const size_t cellbase = ((size_t)bh << 20) + ((size_t)i0 << 10);

    // prefetch mask into registers (NT); loads fly during the LDS scatter
    uint32_t mb[8];
    vi4      mi[8];
    if (mask_byte) {
        const uint32_t* mp = (const uint32_t*)maskp + (cellbase >> 2);
        #pragma unroll
        for (int v = 0; v < 8; ++v)
            mb[v] = __builtin_nontemporal_load(mp + v * 256 + t);
    } else {
        const vi4* mp = (const vi4*)((const int32_t*)maskp + cellbase);
        #pragma unroll
        for (int v = 0; v < 8; ++v)
            mi[v] = __builtin_nontemporal_load(mp + v * 256 + t);
    }

    // 512 records as 256 uint2: thread t -> dd=t>>2, rows 2*(t&3), 2*(t&3)+1
    {
        const uint32_t* pb = pairs + (size_t)bh * (DD * LL);
        const int dd = t >> 2;
        const uint2 pv = ((const uint2*)(pb + dd * LL + i0))[t & 3];
        const int ii0 = 2 * (t & 3), ii1 = ii0 + 1;
        atomicAdd(&acc[ii0 * LL + (int)(pv.x & 1023u)],
                  __uint_as_float(pv.x & 0xFFFFFC00u));
        atomicAdd(&acc[ii1 * LL + (int)(pv.y & 1023u)],
                  __uint_as_float(pv.y & 0xFFFFFC00u));
    }
    __syncthreads();

    vf4* ob = (vf4*)(out + cellbase);
    #pragma unroll
    for (int v = 0; v < 8; ++v) {
        const int p = v * 256 + t;                  // vf4 group in [0,2048)
        const vf4 a = acc4[p];
        int mx, my, mz, mw2;
        if (mask_byte) {
            const uint32_t m = mb[v];
            mx = (int)(m & 0xFFu); my = (int)((m >> 8) & 0xFFu);
            mz = (int)((m >> 16) & 0xFFu); mw2 = (int)(m >> 24);
        } else {
            mx = mi[v].x; my = mi[v].y; mz = mi[v].z; mw2 = mi[v].w;
        }
        vf4 r;
        r.x = mx  ? 0.f : a.x;
        r.y = my  ? 0.f : a.y;
        r.z = mz  ? 0.f : a.z;
        r.w = mw2 ? 0.f : a.w;
        __builtin_nontemporal_store(r, ob + p);
    }
}

extern "C" void kernel_launch(void* const* d_in, const int* in_sizes, int n_in,
                              void* d_out, int out_size, void* d_ws, size_t ws_size,
                              hipStream_t stream) {
    const float* q = (const float*)d_in[0];
    const float* k = (const float*)d_in[1];
    const void* mask = d_in[2];
    uint32_t* pairs = (uint32_t*)d_ws;
    uint32_t* qt = pairs + MAT_WORDS;
    uint32_t* kt = qt + MAT_WORDS;

    const bool ws_ok = (ws_size >= WS_BYTES);
    hipError_t e0 = hipSuccess, e1 = hipSuccess, e2 = hipSuccess;
    (void)hipGetLastError();

    if (ws_ok) {
        swd3_transpose<<<NBH * 16, 256, 0, stream>>>(q, k, qt, kt);
        e0 = hipGetLastError();
        swd3_phase1<<<NBH * DD / 4, 256, 0, stream>>>(qt, kt, pairs);
        e1 = hipGetLastError();
        swd3_phase2<<<NBH * 128, 256, 0, stream>>>(pairs, mask, (float*)d_out);
        e2 = hipGetLastError();
    }

    if (!ws_ok || e0 != hipSuccess || e1 != hipSuccess || e2 != hipSuccess) {
        // Diagnostic stamp (fp32 codes): absmax reveals which enqueue failed.
        static float h_stamp[8];
        h_stamp[0] = !ws_ok ? (9000.0f + (float)(ws_size >> 20))
                            : (1000.0f + (float)(int)e0);
        h_stamp[1] = 2000.0f + (float)(int)e1;
        h_stamp[2] = 3000.0f + (float)(int)e2;
        h_stamp[3] = h_stamp[0];
        hipMemcpyAsync(d_out, h_stamp, sizeof(h_stamp),
                       hipMemcpyHostToDevice, stream);
    }
}